// Round 13
// baseline (160.909 us; speedup 1.0000x reference)
//
#include <hip/hip_runtime.h>
#include <math.h>

#define BB 64
#define TT 1024
#define CC 64
#define HH 32
#define KNN 10
#define SPLIT 8
#define CHUNK (TT / SPLIT)   // 128 rows per wave-chunk; 64 tiles of 2 rows

typedef float v2f __attribute__((ext_vector_type(2)));
typedef float v4f __attribute__((ext_vector_type(4)));

__device__ __forceinline__ v2f pk_fma_vv(v2f a, v2f b, v2f c) {
    v2f d;
    asm("v_pk_fma_f32 %0, %1, %2, %3" : "=v"(d) : "v"(a), "v"(b), "v"(c));
    return d;
}
__device__ __forceinline__ v2f pk_mul_vv(v2f a, v2f b) {
    v2f d;
    asm("v_pk_mul_f32 %0, %1, %2" : "=v"(d) : "v"(a), "v"(b));
    return d;
}
__device__ __forceinline__ v2f pk_add_vv(v2f a, v2f b) {
    v2f d;
    asm("v_pk_add_f32 %0, %1, %2" : "=v"(d) : "v"(a), "v"(b));
    return d;
}
__device__ __forceinline__ unsigned umn(unsigned a, unsigned b) { return a < b ? a : b; }
__device__ __forceinline__ unsigned umx(unsigned a, unsigned b) { return a > b ? a : b; }

// ---------------- Kernel A: h = x@W1 + b1, hsq[row] = 0.5*|h|^2 * 2^20 -------
__global__ __launch_bounds__(256) void h_kernel(
    const float* __restrict__ x, const float* __restrict__ W1,
    const float* __restrict__ b1, float* __restrict__ h, float* __restrict__ hsq)
{
    __shared__ float w1s[CC][HH];
    __shared__ float b1s[HH];
    int tid = threadIdx.x;
    for (int i = tid; i < CC * HH; i += 256) w1s[i >> 5][i & 31] = W1[i];
    if (tid < HH) b1s[tid] = b1[tid];
    __syncthreads();

    int row = blockIdx.x * 256 + tid;
    const float4* xr = (const float4*)(x + (size_t)row * CC);
    float acc[HH];
    #pragma unroll
    for (int j = 0; j < HH; ++j) acc[j] = b1s[j];
    #pragma unroll
    for (int c4 = 0; c4 < CC / 4; ++c4) {
        float4 xv = xr[c4];
        #pragma unroll
        for (int j = 0; j < HH; ++j) {
            acc[j] = fmaf(xv.x, w1s[c4 * 4 + 0][j], acc[j]);
            acc[j] = fmaf(xv.y, w1s[c4 * 4 + 1][j], acc[j]);
            acc[j] = fmaf(xv.z, w1s[c4 * 4 + 2][j], acc[j]);
            acc[j] = fmaf(xv.w, w1s[c4 * 4 + 3][j], acc[j]);
        }
    }
    float s = 0.f;
    #pragma unroll
    for (int j = 0; j < HH; ++j) s = fmaf(acc[j], acc[j], s);
    float* hr = h + (size_t)row * HH;
    #pragma unroll
    for (int q = 0; q < HH / 4; ++q) {
        float4 v = { acc[4*q], acc[4*q+1], acc[4*q+2], acc[4*q+3] };
        ((float4*)hr)[q] = v;
    }
    hsq[row] = 0.5f * s * 1048576.0f;      // pre-scaled by 2^20 for key fma
}

// key from one candidate row read out of LDS (uniform addr -> broadcast)
__device__ __forceinline__ unsigned make_key_v(const v2f* cr, float chs20,
                                               v2f cinit, const v2f* hn,
                                               int i, int self_i) {
    v2f accA = pk_fma_vv(hn[0], cr[0], cinit);
    v2f accB = pk_mul_vv(hn[1], cr[1]);
    #pragma unroll
    for (int q = 2; q < 16; q += 2) {
        accA = pk_fma_vv(hn[q],     cr[q],     accA);
        accB = pk_fma_vv(hn[q + 1], cr[q + 1], accB);
    }
    v2f s2 = pk_add_vv(accA, accB);
    float sum  = s2[0] + s2[1];                       // (0.5 sq_t + 1) - dot
    float keyf = fmaf(sum, 1048576.0f, chs20);        // *2^20 + 0.5 sq_s*2^20
    unsigned ki = (unsigned)keyf;                     // trunc, monotone (>0)
    ki = umn(ki, 0x1FFFFFFu);                         // clamp: never top-10
    unsigned packed = (ki << 7) | (unsigned)i;
    return (i == self_i) ? 0xFFFFFFFFu : packed;
}

#define INSERT_PAIR(kE, kO) do {                                       \
    unsigned lo_ = umn(kE, kO), hi_ = umx(kE, kO);                     \
    bd9 = umn(umn(bd9, umx(bd8, lo_)), umx(bd7, hi_));                 \
    bd8 = umn(umn(bd8, umx(bd7, lo_)), umx(bd6, hi_));                 \
    bd7 = umn(umn(bd7, umx(bd6, lo_)), umx(bd5, hi_));                 \
    bd6 = umn(umn(bd6, umx(bd5, lo_)), umx(bd4, hi_));                 \
    bd5 = umn(umn(bd5, umx(bd4, lo_)), umx(bd3, hi_));                 \
    bd4 = umn(umn(bd4, umx(bd3, lo_)), umx(bd2, hi_));                 \
    bd3 = umn(umn(bd3, umx(bd2, lo_)), umx(bd1, hi_));                 \
    bd2 = umn(umn(bd2, umx(bd1, lo_)), umx(bd0, hi_));                 \
    bd1 = umn(umn(bd1, umx(bd0, lo_)), hi_);                           \
    bd0 = umn(bd0, lo_);                                               \
} while (0)

// ------------- Kernel B: kNN + laplace smooth + tanh + W2 GEMM ---------------
// 512 thr = 8 waves; block owns 64 rows (1/lane); wave w scans candidates
// [w*128, w*128+128). Candidate stream: wave-PRIVATE LDS ring (4 bufs x 2
// rows); staged by coalesced per-lane global_load_dword (3-tile lead, deep
// vmcnt) + ds_write; consumed via uniform-address ds_read (in-order DS ->
// partial lgkm waits pipeline, unlike OOO SMEM which forced lgkmcnt(0)
// drains). hsq lives in 2 VGPRs/lane, broadcast per-tile via readlane ->
// ZERO SMEM in the hot loop. XCD-aware batch-grouped swizzle kept (r12).
__global__ __launch_bounds__(512, 4) void lap_kernel(
    const float* __restrict__ h, const float* __restrict__ hsq,
    const float* __restrict__ W2, const float* __restrict__ b2,
    float* __restrict__ out)
{
    __shared__ unsigned s_key[SPLIT][64][KNN];   // 20.5 KB (a_pool aliases)
    __shared__ float lbuf[SPLIT][4][64];         // 8 KB: per-wave 4x2-row ring
    __shared__ float e_wk[64][KNN];              // 2.5 KB
    __shared__ short e_id[64][KNN];              // 1.25 KB
    __shared__ float e_inv[64];                  // 256 B
    __shared__ float w2s[HH][HH];                // 4 KB
    __shared__ float b2s[HH];

    int tid  = threadIdx.x;
    int lane = tid & 63;
    int wid  = __builtin_amdgcn_readfirstlane(tid >> 6);   // chunk id 0..7

    // bijective XCD/batch swizzle: g -> (xcd, l); batch from (xcd, l&7)
    int g   = blockIdx.x;
    int l   = g >> 3;
    int bb  = ((g & 7) << 3) | (l & 7);   // batch
    int rb  = (l >> 3) << 6;              // row base within batch
    int row = rb + lane;

    for (int i = tid; i < HH * HH; i += 512) w2s[i >> 5][i & 31] = W2[i];
    if (tid < HH) b2s[tid] = b2[tid];

    const float* hb  = h   + (size_t)bb * TT * HH;
    const float* sqb = hsq + (size_t)bb * TT;

    // own row, negated (16 x float2, VGPRs)
    v2f hn[16];
    {
        const v4f* hrp = (const v4f*)(hb + (size_t)row * HH);
        #pragma unroll
        for (int q = 0; q < 8; ++q) {
            v4f v = hrp[q];
            hn[2*q]   = (v2f){ -v[0], -v[1] };
            hn[2*q+1] = (v2f){ -v[2], -v[3] };
        }
    }
    // per-lane bias: 0.5*sq_t + 1 (unscale the 2^20-scaled array)
    v2f cinit = (v2f){ fmaf(sqb[row], 9.5367431640625e-07f, 1.0f), 0.0f };

    int s0 = wid * CHUNK;
    int self_i = row - s0;                      // chunk-local self position
    if ((unsigned)self_i >= (unsigned)CHUNK) self_i = -1;

    // chunk hsq (pre-scaled *2^20) into 2 VGPRs/lane: lane j holds
    // hsq[s0+2j], hsq[s0+2j+1]; broadcast per tile via readlane(t).
    float2 hsq2 = *(const float2*)(sqb + s0 + 2 * lane);

    unsigned bd0 = 0xFFFFFFFFu, bd1 = 0xFFFFFFFFu, bd2 = 0xFFFFFFFFu,
             bd3 = 0xFFFFFFFFu, bd4 = 0xFFFFFFFFu, bd5 = 0xFFFFFFFFu,
             bd6 = 0xFFFFFFFFu, bd7 = 0xFFFFFFFFu, bd8 = 0xFFFFFFFFu,
             bd9 = 0xFFFFFFFFu;

    // chunk candidate data: 64 tiles x (2 rows = 64 floats = 256 B)
    const float* src = hb + (size_t)s0 * HH;

    // prologue: stage tiles 0,1,2 (lane i carries float i of the tile)
    #pragma unroll
    for (int t = 0; t < 3; ++t)
        lbuf[wid][t][lane] = src[t * 64 + lane];

    #pragma unroll 2
    for (int t = 0; t < 64; ++t) {
        // issue prefetch of tile t+3 (wave-uniform branch; deep vmcnt queue)
        float gpre = 0.f;
        bool pf = (t + 3) < 64;
        if (pf) gpre = src[(t + 3) * 64 + lane];

        float chsA = __uint_as_float(
            __builtin_amdgcn_readlane(__float_as_uint(hsq2.x), t));
        float chsB = __uint_as_float(
            __builtin_amdgcn_readlane(__float_as_uint(hsq2.y), t));

        const v2f* pA = (const v2f*)&lbuf[wid][t & 3][0];
        unsigned kE = make_key_v(pA,      chsA, cinit, hn, 2 * t,     self_i);
        unsigned kO = make_key_v(pA + 16, chsB, cinit, hn, 2 * t + 1, self_i);

        INSERT_PAIR(kE, kO);

        // land the prefetch into the ring slot (== slot of tile t-1, dead)
        if (pf) lbuf[wid][(t + 3) & 3][lane] = gpre;
    }

    s_key[wid][lane][0] = bd0; s_key[wid][lane][1] = bd1;
    s_key[wid][lane][2] = bd2; s_key[wid][lane][3] = bd3;
    s_key[wid][lane][4] = bd4; s_key[wid][lane][5] = bd5;
    s_key[wid][lane][6] = bd6; s_key[wid][lane][7] = bd7;
    s_key[wid][lane][8] = bd8; s_key[wid][lane][9] = bd9;
    __syncthreads();

    if (wid == 0) {
        // 8-way merge of sorted 10-lists (strict < keeps lowest chunk on tie)
        unsigned k0 = s_key[0][lane][0], k1 = s_key[1][lane][0];
        unsigned k2 = s_key[2][lane][0], k3 = s_key[3][lane][0];
        unsigned k4 = s_key[4][lane][0], k5 = s_key[5][lane][0];
        unsigned k6 = s_key[6][lane][0], k7 = s_key[7][lane][0];
        int p0=0,p1=0,p2=0,p3=0,p4=0,p5=0,p6=0,p7=0;
        float wsum = 0.f;
        #pragma unroll
        for (int j = 0; j < KNN; ++j) {
            unsigned mn = k0; int c = 0;
            if (k1 < mn) { mn = k1; c = 1; }
            if (k2 < mn) { mn = k2; c = 2; }
            if (k3 < mn) { mn = k3; c = 3; }
            if (k4 < mn) { mn = k4; c = 4; }
            if (k5 < mn) { mn = k5; c = 5; }
            if (k6 < mn) { mn = k6; c = 6; }
            if (k7 < mn) { mn = k7; c = 7; }
            // weight from the kept key: key = (0.5*d2 + 1)*2^20
            float kf = (float)(mn >> 7) * 9.5367431640625e-07f;
            float wk = expf(1.0f - kf);               // exp(-0.5*d2)
            wsum += wk;
            e_id[lane][j] = (short)((int)(mn & 127u) + (c << 7));
            e_wk[lane][j] = wk;
            if      (c == 0) { ++p0; k0 = (p0 < KNN) ? s_key[0][lane][p0] : 0xFFFFFFFFu; }
            else if (c == 1) { ++p1; k1 = (p1 < KNN) ? s_key[1][lane][p1] : 0xFFFFFFFFu; }
            else if (c == 2) { ++p2; k2 = (p2 < KNN) ? s_key[2][lane][p2] : 0xFFFFFFFFu; }
            else if (c == 3) { ++p3; k3 = (p3 < KNN) ? s_key[3][lane][p3] : 0xFFFFFFFFu; }
            else if (c == 4) { ++p4; k4 = (p4 < KNN) ? s_key[4][lane][p4] : 0xFFFFFFFFu; }
            else if (c == 5) { ++p5; k5 = (p5 < KNN) ? s_key[5][lane][p5] : 0xFFFFFFFFu; }
            else if (c == 6) { ++p6; k6 = (p6 < KNN) ? s_key[6][lane][p6] : 0xFFFFFFFFu; }
            else             { ++p7; k7 = (p7 < KNN) ? s_key[7][lane][p7] : 0xFFFFFFFFu; }
        }
        e_inv[lane] = 1.0f / (wsum + 1e-8f);
    }
    __syncthreads();

    // gather + smooth + tanh, parallel over (row, 4-dim group); a_pool
    // aliases s_key (dead after merge). Stride 36 -> 16B-aligned rows.
    float* a_pool = (float*)&s_key[0][0][0];
    {
        int r  = tid >> 3;             // 0..63
        int g2 = (tid & 7) << 2;       // dim base 0,4,...,28
        float ax = 0.f, ay = 0.f, az = 0.f, aw = 0.f;
        #pragma unroll
        for (int k = 0; k < KNN; ++k) {
            int idx  = e_id[r][k];
            float wk = e_wk[r][k];
            const float4 nv = *(const float4*)(hb + (size_t)idx * HH + g2);
            ax = fmaf(wk, nv.x, ax);
            ay = fmaf(wk, nv.y, ay);
            az = fmaf(wk, nv.z, az);
            aw = fmaf(wk, nv.w, aw);
        }
        float inv = e_inv[r];
        const float4 hv = *(const float4*)(hb + (size_t)(rb + r) * HH + g2);
        float4 av;
        av.x = tanhf(fmaf(-ax, inv, hv.x));
        av.y = tanhf(fmaf(-ay, inv, hv.y));
        av.z = tanhf(fmaf(-az, inv, hv.z));
        av.w = tanhf(fmaf(-aw, inv, hv.w));
        *(float4*)&a_pool[r * 36 + g2] = av;
    }
    __syncthreads();

    // out = a @ W2 + b2 ; thread -> (row r, 4 consecutive output dims)
    int r   = tid >> 3;
    int c0_ = (tid & 7) << 2;
    float o[4];
    #pragma unroll
    for (int u = 0; u < 4; ++u) o[u] = b2s[c0_ + u];
    #pragma unroll
    for (int j = 0; j < HH; ++j) {
        float av = a_pool[r * 36 + j];
        #pragma unroll
        for (int u = 0; u < 4; ++u) o[u] = fmaf(av, w2s[j][c0_ + u], o[u]);
    }
    float* op = out + ((size_t)bb * TT + rb + r) * HH + c0_;
    float4 o1 = { o[0], o[1], o[2], o[3] };
    *((float4*)op) = o1;
}

extern "C" void kernel_launch(void* const* d_in, const int* in_sizes, int n_in,
                              void* d_out, int out_size, void* d_ws, size_t ws_size,
                              hipStream_t stream) {
    const float* x  = (const float*)d_in[0];
    const float* W1 = (const float*)d_in[1];
    const float* b1 = (const float*)d_in[2];
    const float* W2 = (const float*)d_in[3];
    const float* b2 = (const float*)d_in[4];
    float* outp = (float*)d_out;

    float* h   = (float*)d_ws;
    float* hsq = h + (size_t)BB * TT * HH;

    h_kernel<<<(BB * TT) / 256, 256, 0, stream>>>(x, W1, b1, h, hsq);
    lap_kernel<<<BB * (TT / 64), 512, 0, stream>>>(h, hsq, W2, b2, outp);
}

// Round 14
// 131.105 us; speedup vs baseline: 1.2273x; 1.2273x over previous
//
#include <hip/hip_runtime.h>
#include <math.h>

#define BB 64
#define TT 1024
#define CC 64
#define HH 32
#define KNN 10
#define SPLIT 4
#define CHUNK (TT / SPLIT)   // 256

typedef float v2f __attribute__((ext_vector_type(2)));
typedef float v4f __attribute__((ext_vector_type(4)));

__device__ __forceinline__ v2f pk_fma_vs(v2f a_v, v2f b_s, v2f c_v) {
    v2f d;
    asm("v_pk_fma_f32 %0, %1, %2, %3" : "=v"(d) : "v"(a_v), "s"(b_s), "v"(c_v));
    return d;
}
__device__ __forceinline__ v2f pk_mul_vs(v2f a_v, v2f b_s) {
    v2f d;
    asm("v_pk_mul_f32 %0, %1, %2" : "=v"(d) : "v"(a_v), "s"(b_s));
    return d;
}
__device__ __forceinline__ v2f pk_add_vv(v2f a, v2f b) {
    v2f d;
    asm("v_pk_add_f32 %0, %1, %2" : "=v"(d) : "v"(a), "v"(b));
    return d;
}
__device__ __forceinline__ unsigned umn(unsigned a, unsigned b) { return a < b ? a : b; }
__device__ __forceinline__ unsigned umx(unsigned a, unsigned b) { return a > b ? a : b; }

// ---------------- Kernel A: h = x@W1 + b1, hsq[row] = 0.5*|h|^2 * 2^20 -------
__global__ __launch_bounds__(256) void h_kernel(
    const float* __restrict__ x, const float* __restrict__ W1,
    const float* __restrict__ b1, float* __restrict__ h, float* __restrict__ hsq)
{
    __shared__ float w1s[CC][HH];
    __shared__ float b1s[HH];
    int tid = threadIdx.x;
    for (int i = tid; i < CC * HH; i += 256) w1s[i >> 5][i & 31] = W1[i];
    if (tid < HH) b1s[tid] = b1[tid];
    __syncthreads();

    int row = blockIdx.x * 256 + tid;
    const float4* xr = (const float4*)(x + (size_t)row * CC);
    float acc[HH];
    #pragma unroll
    for (int j = 0; j < HH; ++j) acc[j] = b1s[j];
    #pragma unroll
    for (int c4 = 0; c4 < CC / 4; ++c4) {
        float4 xv = xr[c4];
        #pragma unroll
        for (int j = 0; j < HH; ++j) {
            acc[j] = fmaf(xv.x, w1s[c4 * 4 + 0][j], acc[j]);
            acc[j] = fmaf(xv.y, w1s[c4 * 4 + 1][j], acc[j]);
            acc[j] = fmaf(xv.z, w1s[c4 * 4 + 2][j], acc[j]);
            acc[j] = fmaf(xv.w, w1s[c4 * 4 + 3][j], acc[j]);
        }
    }
    float s = 0.f;
    #pragma unroll
    for (int j = 0; j < HH; ++j) s = fmaf(acc[j], acc[j], s);
    float* hr = h + (size_t)row * HH;
    #pragma unroll
    for (int q = 0; q < HH / 4; ++q) {
        float4 v = { acc[4*q], acc[4*q+1], acc[4*q+2], acc[4*q+3] };
        ((float4*)hr)[q] = v;
    }
    hsq[row] = 0.5f * s * 1048576.0f;      // pre-scaled by 2^20 for key fma
}

__device__ __forceinline__ unsigned make_key(const v2f* cr, float chs20,
                                             v2f cinit, const v2f* hn,
                                             int i, int self_i) {
    v2f accA = pk_fma_vs(hn[0], cr[0], cinit);
    v2f accB = pk_mul_vs(hn[1], cr[1]);
    #pragma unroll
    for (int q = 2; q < 16; q += 2) {
        accA = pk_fma_vs(hn[q],     cr[q],     accA);
        accB = pk_fma_vs(hn[q + 1], cr[q + 1], accB);
    }
    v2f s2 = pk_add_vv(accA, accB);
    float sum  = s2[0] + s2[1];                       // (0.5 sq_t + 1) - dot
    float keyf = fmaf(sum, 1048576.0f, chs20);        // *2^20 + 0.5 sq_s*2^20
    unsigned ki = (unsigned)keyf;                     // trunc, monotone (>0)
    ki = umn(ki, 0xFFFFFFu);                          // clamp: never top-10
    unsigned packed = (ki << 8) | (unsigned)i;        // 8-bit chunk-local idx
    return (i == self_i) ? 0xFFFFFFFFu : packed;
}

// ------------- Kernel B: kNN + laplace smooth + tanh + W2 GEMM ---------------
// 256 thr = 4 waves; block owns 64 rows (1/lane); wave w scans candidates
// [w*256, (w+1)*256) (wave-uniform -> s_load/SGPR). Ping-pong row buffers.
// Smaller blocks than r12 (512): same grid/wave count, but 8 blocks/CU can
// co-reside (vs 2 measured at 512 thr) -> 8 waves/SIMD to hide the per-body
// lgkmcnt(0) SMEM drain. XCD-aware batch-grouped swizzle kept (r12).
__global__ __launch_bounds__(256, 8) void lap_kernel(
    const float* __restrict__ h, const float* __restrict__ hsq,
    const float* __restrict__ W2, const float* __restrict__ b2,
    float* __restrict__ out)
{
    __shared__ unsigned s_key[SPLIT][64][KNN];   // 10.25 KB (a_pool aliases)
    __shared__ float e_wk[64][KNN];              // 2.5 KB
    __shared__ short e_id[64][KNN];              // 1.25 KB
    __shared__ float e_inv[64];                  // 256 B
    __shared__ float w2s[HH][HH];                // 4 KB
    __shared__ float b2s[HH];

    int tid  = threadIdx.x;
    int lane = tid & 63;
    int wid  = __builtin_amdgcn_readfirstlane(tid >> 6);   // chunk id 0..3

    // bijective XCD/batch swizzle: g -> (xcd, l); batch from (xcd, l&7)
    int g   = blockIdx.x;
    int l   = g >> 3;
    int bb  = ((g & 7) << 3) | (l & 7);   // batch
    int rb  = (l >> 3) << 6;              // row base within batch
    int row = rb + lane;

    for (int i = tid; i < HH * HH; i += 256) w2s[i >> 5][i & 31] = W2[i];
    if (tid < HH) b2s[tid] = b2[tid];

    const float* hb  = h   + (size_t)bb * TT * HH;
    const float* sqb = hsq + (size_t)bb * TT;

    // own row, negated (16 x float2, VGPRs)
    v2f hn[16];
    {
        const v4f* hrp = (const v4f*)(hb + (size_t)row * HH);
        #pragma unroll
        for (int q = 0; q < 8; ++q) {
            v4f v = hrp[q];
            hn[2*q]   = (v2f){ -v[0], -v[1] };
            hn[2*q+1] = (v2f){ -v[2], -v[3] };
        }
    }
    // per-lane bias: 0.5*sq_t + 1 (unscale the 2^20-scaled array)
    v2f cinit = (v2f){ fmaf(sqb[row], 9.5367431640625e-07f, 1.0f), 0.0f };

    int s0 = wid * CHUNK;
    int self_i = row - s0;                      // chunk-local self position
    if ((unsigned)self_i >= (unsigned)CHUNK) self_i = -1;

    unsigned bd0 = 0xFFFFFFFFu, bd1 = 0xFFFFFFFFu, bd2 = 0xFFFFFFFFu,
             bd3 = 0xFFFFFFFFu, bd4 = 0xFFFFFFFFu, bd5 = 0xFFFFFFFFu,
             bd6 = 0xFFFFFFFFu, bd7 = 0xFFFFFFFFu, bd8 = 0xFFFFFFFFu,
             bd9 = 0xFFFFFFFFu;

    // ping-pong buffers (SGPR via "s"-constrained consumers; no copies)
    v2f bufA[16], bufB[16]; float chsA, chsB;
    {
        const v2f* pA = (const v2f*)(hb + (size_t)s0 * HH);
        const v2f* pB = (const v2f*)(hb + (size_t)(s0 + 1) * HH);
        #pragma unroll
        for (int q = 0; q < 16; ++q) { bufA[q] = pA[q]; bufB[q] = pB[q]; }
        chsA = sqb[s0]; chsB = sqb[s0 + 1];
    }

    for (int i = 0; i < CHUNK; i += 2) {
        unsigned kE = make_key(bufA, chsA, cinit, hn, i,     self_i);
        unsigned kO = make_key(bufB, chsB, cinit, hn, i + 1, self_i);

        // issue next pair (tail clamps: harmless reload, never used)
        int i2 = (i + 2 < CHUNK) ? i + 2 : CHUNK - 1;
        int i3 = (i + 3 < CHUNK) ? i + 3 : CHUNK - 1;
        {
            const v2f* pA = (const v2f*)(hb + (size_t)(s0 + i2) * HH);
            const v2f* pB = (const v2f*)(hb + (size_t)(s0 + i3) * HH);
            #pragma unroll
            for (int q = 0; q < 16; ++q) { bufA[q] = pA[q]; bufB[q] = pB[q]; }
            chsA = sqb[s0 + i2]; chsB = sqb[s0 + i3];
        }

        // merged sorted-pair insert into ascending top-10 (min3/max fusable)
        unsigned lo = umn(kE, kO), hi = umx(kE, kO);
        bd9 = umn(umn(bd9, umx(bd8, lo)), umx(bd7, hi));
        bd8 = umn(umn(bd8, umx(bd7, lo)), umx(bd6, hi));
        bd7 = umn(umn(bd7, umx(bd6, lo)), umx(bd5, hi));
        bd6 = umn(umn(bd6, umx(bd5, lo)), umx(bd4, hi));
        bd5 = umn(umn(bd5, umx(bd4, lo)), umx(bd3, hi));
        bd4 = umn(umn(bd4, umx(bd3, lo)), umx(bd2, hi));
        bd3 = umn(umn(bd3, umx(bd2, lo)), umx(bd1, hi));
        bd2 = umn(umn(bd2, umx(bd1, lo)), umx(bd0, hi));
        bd1 = umn(umn(bd1, umx(bd0, lo)), hi);
        bd0 = umn(bd0, lo);
    }

    s_key[wid][lane][0] = bd0; s_key[wid][lane][1] = bd1;
    s_key[wid][lane][2] = bd2; s_key[wid][lane][3] = bd3;
    s_key[wid][lane][4] = bd4; s_key[wid][lane][5] = bd5;
    s_key[wid][lane][6] = bd6; s_key[wid][lane][7] = bd7;
    s_key[wid][lane][8] = bd8; s_key[wid][lane][9] = bd9;
    __syncthreads();

    if (wid == 0) {
        // 4-way merge of sorted 10-lists (strict < keeps lowest chunk on tie)
        unsigned k0 = s_key[0][lane][0], k1 = s_key[1][lane][0];
        unsigned k2 = s_key[2][lane][0], k3 = s_key[3][lane][0];
        int p0 = 0, p1 = 0, p2 = 0, p3 = 0;
        float wsum = 0.f;
        #pragma unroll
        for (int j = 0; j < KNN; ++j) {
            unsigned mn = k0; int c = 0;
            if (k1 < mn) { mn = k1; c = 1; }
            if (k2 < mn) { mn = k2; c = 2; }
            if (k3 < mn) { mn = k3; c = 3; }
            // weight from the kept key: key = (0.5*d2 + 1)*2^20
            float kf = (float)(mn >> 8) * 9.5367431640625e-07f;
            float wk = expf(1.0f - kf);               // exp(-0.5*d2)
            wsum += wk;
            e_id[lane][j] = (short)((int)(mn & 255u) + (c << 8));
            e_wk[lane][j] = wk;
            if      (c == 0) { ++p0; k0 = (p0 < KNN) ? s_key[0][lane][p0] : 0xFFFFFFFFu; }
            else if (c == 1) { ++p1; k1 = (p1 < KNN) ? s_key[1][lane][p1] : 0xFFFFFFFFu; }
            else if (c == 2) { ++p2; k2 = (p2 < KNN) ? s_key[2][lane][p2] : 0xFFFFFFFFu; }
            else             { ++p3; k3 = (p3 < KNN) ? s_key[3][lane][p3] : 0xFFFFFFFFu; }
        }
        e_inv[lane] = 1.0f / (wsum + 1e-8f);
    }
    __syncthreads();

    // gather + smooth + tanh, parallel over (row, 8-dim group); a_pool
    // aliases s_key (dead after merge). Stride 36 -> 16B-aligned rows.
    float* a_pool = (float*)&s_key[0][0][0];
    {
        int r  = tid >> 2;             // 0..63
        int g2 = (tid & 3) << 3;       // dim base 0,8,16,24
        float a0 = 0.f, a1 = 0.f, a2 = 0.f, a3 = 0.f;
        float a4 = 0.f, a5 = 0.f, a6 = 0.f, a7 = 0.f;
        #pragma unroll
        for (int k = 0; k < KNN; ++k) {
            int idx  = e_id[r][k];
            float wk = e_wk[r][k];
            const float4 n1 = *(const float4*)(hb + (size_t)idx * HH + g2);
            const float4 n2 = *(const float4*)(hb + (size_t)idx * HH + g2 + 4);
            a0 = fmaf(wk, n1.x, a0); a1 = fmaf(wk, n1.y, a1);
            a2 = fmaf(wk, n1.z, a2); a3 = fmaf(wk, n1.w, a3);
            a4 = fmaf(wk, n2.x, a4); a5 = fmaf(wk, n2.y, a5);
            a6 = fmaf(wk, n2.z, a6); a7 = fmaf(wk, n2.w, a7);
        }
        float inv = e_inv[r];
        const float4 h1 = *(const float4*)(hb + (size_t)(rb + r) * HH + g2);
        const float4 h2 = *(const float4*)(hb + (size_t)(rb + r) * HH + g2 + 4);
        float4 o1, o2;
        o1.x = tanhf(fmaf(-a0, inv, h1.x)); o1.y = tanhf(fmaf(-a1, inv, h1.y));
        o1.z = tanhf(fmaf(-a2, inv, h1.z)); o1.w = tanhf(fmaf(-a3, inv, h1.w));
        o2.x = tanhf(fmaf(-a4, inv, h2.x)); o2.y = tanhf(fmaf(-a5, inv, h2.y));
        o2.z = tanhf(fmaf(-a6, inv, h2.z)); o2.w = tanhf(fmaf(-a7, inv, h2.w));
        *(float4*)&a_pool[r * 36 + g2]     = o1;
        *(float4*)&a_pool[r * 36 + g2 + 4] = o2;
    }
    __syncthreads();

    // out = a @ W2 + b2 ; thread -> (row r, 8 consecutive output dims)
    int r   = tid >> 2;
    int c0_ = (tid & 3) << 3;
    float o[8];
    #pragma unroll
    for (int u = 0; u < 8; ++u) o[u] = b2s[c0_ + u];
    #pragma unroll
    for (int j = 0; j < HH; ++j) {
        float av = a_pool[r * 36 + j];
        #pragma unroll
        for (int u = 0; u < 8; ++u) o[u] = fmaf(av, w2s[j][c0_ + u], o[u]);
    }
    float* op = out + ((size_t)bb * TT + rb + r) * HH + c0_;
    float4 o1 = { o[0], o[1], o[2], o[3] };
    float4 o2 = { o[4], o[5], o[6], o[7] };
    ((float4*)op)[0] = o1;
    ((float4*)op)[1] = o2;
}

extern "C" void kernel_launch(void* const* d_in, const int* in_sizes, int n_in,
                              void* d_out, int out_size, void* d_ws, size_t ws_size,
                              hipStream_t stream) {
    const float* x  = (const float*)d_in[0];
    const float* W1 = (const float*)d_in[1];
    const float* b1 = (const float*)d_in[2];
    const float* W2 = (const float*)d_in[3];
    const float* b2 = (const float*)d_in[4];
    float* outp = (float*)d_out;

    float* h   = (float*)d_ws;
    float* hsq = h + (size_t)BB * TT * HH;

    h_kernel<<<(BB * TT) / 256, 256, 0, stream>>>(x, W1, b1, h, hsq);
    lap_kernel<<<BB * (TT / 64), 256, 0, stream>>>(h, hsq, W2, b2, outp);
}

// Round 15
// 81.637 us; speedup vs baseline: 1.9710x; 1.6060x over previous
//
#include <hip/hip_runtime.h>
#include <math.h>

#define BB 64
#define TT 1024
#define CC 64
#define HH 32
#define KNN 10

typedef float v4f __attribute__((ext_vector_type(4)));
typedef _Float16 f16x8 __attribute__((ext_vector_type(8)));

__device__ __forceinline__ unsigned umn(unsigned a, unsigned b) { return a < b ? a : b; }
__device__ __forceinline__ unsigned umx(unsigned a, unsigned b) { return a > b ? a : b; }

// ---------------- Kernel A: h = x@W1 + b1, hsq[row] = 0.5*|h|^2 * 2^20 -------
__global__ __launch_bounds__(256) void h_kernel(
    const float* __restrict__ x, const float* __restrict__ W1,
    const float* __restrict__ b1, float* __restrict__ h, float* __restrict__ hsq)
{
    __shared__ float w1s[CC][HH];
    __shared__ float b1s[HH];
    int tid = threadIdx.x;
    for (int i = tid; i < CC * HH; i += 256) w1s[i >> 5][i & 31] = W1[i];
    if (tid < HH) b1s[tid] = b1[tid];
    __syncthreads();

    int row = blockIdx.x * 256 + tid;
    const float4* xr = (const float4*)(x + (size_t)row * CC);
    float acc[HH];
    #pragma unroll
    for (int j = 0; j < HH; ++j) acc[j] = b1s[j];
    #pragma unroll
    for (int c4 = 0; c4 < CC / 4; ++c4) {
        float4 xv = xr[c4];
        #pragma unroll
        for (int j = 0; j < HH; ++j) {
            acc[j] = fmaf(xv.x, w1s[c4 * 4 + 0][j], acc[j]);
            acc[j] = fmaf(xv.y, w1s[c4 * 4 + 1][j], acc[j]);
            acc[j] = fmaf(xv.z, w1s[c4 * 4 + 2][j], acc[j]);
            acc[j] = fmaf(xv.w, w1s[c4 * 4 + 3][j], acc[j]);
        }
    }
    float s = 0.f;
    #pragma unroll
    for (int j = 0; j < HH; ++j) s = fmaf(acc[j], acc[j], s);
    float* hr = h + (size_t)row * HH;
    #pragma unroll
    for (int q = 0; q < HH / 4; ++q) {
        float4 v = { acc[4*q], acc[4*q+1], acc[4*q+2], acc[4*q+3] };
        ((float4*)hr)[q] = v;
    }
    hsq[row] = 0.5f * s * 1048576.0f;      // pre-scaled by 2^20 for key math
}

#define INSERT_PAIR(kE, kO) do {                                       \
    unsigned lo_ = umn(kE, kO), hi_ = umx(kE, kO);                     \
    bd9 = umn(umn(bd9, umx(bd8, lo_)), umx(bd7, hi_));                 \
    bd8 = umn(umn(bd8, umx(bd7, lo_)), umx(bd6, hi_));                 \
    bd7 = umn(umn(bd7, umx(bd6, lo_)), umx(bd5, hi_));                 \
    bd6 = umn(umn(bd6, umx(bd5, lo_)), umx(bd4, hi_));                 \
    bd5 = umn(umn(bd5, umx(bd4, lo_)), umx(bd3, hi_));                 \
    bd4 = umn(umn(bd4, umx(bd3, lo_)), umx(bd2, hi_));                 \
    bd3 = umn(umn(bd3, umx(bd2, lo_)), umx(bd1, hi_));                 \
    bd2 = umn(umn(bd2, umx(bd1, lo_)), umx(bd0, hi_));                 \
    bd1 = umn(umn(bd1, umx(bd0, lo_)), hi_);                           \
    bd0 = umn(bd0, lo_);                                               \
} while (0)

// ------------- Kernel B: MFMA Gram kNN + laplace smooth + tanh + W2 ----------
// 512 thr = 8 waves. Block: 64 target rows x 1024 candidates.
// Wave w: target group g=w&3 (16 targets), candidate half=w>>2 (512 cands).
// Dot via mfma_f32_16x16x32_f16, 3-term fp16 hi/lo split (err ~2.5e-6).
// A = candidates from LDS (staged fp32->fp16 hi/lo, 64-row tiles, dbuf);
// B = wave's 16 targets in VGPRs. D: col=lane&15 (target), row=(lane>>4)*4+reg
// (candidate) [m89-verified] -> per-lane keys feed the r12 insert network.
// 8 partials per target (2 halves x 4 lane-rows) -> r12's 8-way merge.
__global__ __launch_bounds__(512, 2) void lap_kernel(
    const float* __restrict__ h, const float* __restrict__ hsq,
    const float* __restrict__ W2, const float* __restrict__ b2,
    float* __restrict__ out)
{
    __shared__ _Float16 cah[2][2][64][40];       // 20 KB  [buf][half][row][k]
    __shared__ _Float16 cal[2][2][64][40];       // 20 KB
    __shared__ unsigned s_key[8][64][KNN];       // 20 KB  (a_pool aliases)
    __shared__ float e_wk[64][KNN];              // 2.5 KB
    __shared__ short e_id[64][KNN];              // 1.25 KB
    __shared__ float e_inv[64];                  // 256 B
    __shared__ float w2s[HH][HH];                // 4 KB
    __shared__ float b2s[HH];

    int tid  = threadIdx.x;
    int lane = tid & 63;
    int wid  = __builtin_amdgcn_readfirstlane(tid >> 6);   // 0..7

    // bijective XCD/batch swizzle (r12)
    int g   = blockIdx.x;
    int l   = g >> 3;
    int bb  = ((g & 7) << 3) | (l & 7);   // batch
    int rb  = (l >> 3) << 6;              // target row base within batch

    for (int i = tid; i < HH * HH; i += 512) w2s[i >> 5][i & 31] = W2[i];
    if (tid < HH) b2s[tid] = b2[tid];

    const float* hb  = h   + (size_t)bb * TT * HH;
    const float* sqb = hsq + (size_t)bb * TT;

    int gtg  = wid & 3;          // target group 0..3
    int half = wid >> 2;         // candidate half 0..1
    int n    = lane & 15;        // target within group / A-row within subtile
    int kc   = lane >> 4;        // k-chunk 0..3 / candidate row-quad

    // B fragments: this lane's target row, k-chunk kc (8 fp32 -> fp16 hi/lo)
    int trow = rb + gtg * 16 + n;
    f16x8 Bhi, Blo;
    {
        const float* tp = hb + (size_t)trow * HH + kc * 8;
        float4 f1 = ((const float4*)tp)[0];
        float4 f2 = ((const float4*)tp)[1];
        float tf[8] = { f1.x, f1.y, f1.z, f1.w, f2.x, f2.y, f2.z, f2.w };
        #pragma unroll
        for (int e = 0; e < 8; ++e) {
            _Float16 hh = (_Float16)tf[e];
            Bhi[e] = hh;
            Blo[e] = (_Float16)(tf[e] - (float)hh);
        }
    }
    float cinit20 = sqb[trow] + 1048576.0f;   // (0.5 sq_t + 1) * 2^20

    // self candidate: in this lane's stream iff half matches and row-quad==kc
    int s_local = trow - half * 512;
    bool selfok = ((unsigned)s_local < 512u) && (((s_local >> 2) & 3) == kc);
    int self_t7 = selfok ? (((s_local >> 6) << 4) | (((s_local >> 4) & 3) << 2)
                           | (s_local & 3)) : -1;

    unsigned bd0 = 0xFFFFFFFFu, bd1 = 0xFFFFFFFFu, bd2 = 0xFFFFFFFFu,
             bd3 = 0xFFFFFFFFu, bd4 = 0xFFFFFFFFu, bd5 = 0xFFFFFFFFu,
             bd6 = 0xFFFFFFFFu, bd7 = 0xFFFFFFFFu, bd8 = 0xFFFFFFFFu,
             bd9 = 0xFFFFFFFFu;

    // staging map: thread -> (k-chunk, row, half); coalesced 16 rows/wave
    int st_c = tid & 3, st_r = (tid >> 2) & 63, st_h = tid >> 8;

    auto STAGE = [&](int buf, int t) {
        const float* p = hb + (size_t)(st_h * 512 + t * 64 + st_r) * HH + st_c * 8;
        float4 f1 = ((const float4*)p)[0];
        float4 f2 = ((const float4*)p)[1];
        float fe[8] = { f1.x, f1.y, f1.z, f1.w, f2.x, f2.y, f2.z, f2.w };
        f16x8 hi8, lo8;
        #pragma unroll
        for (int e = 0; e < 8; ++e) {
            _Float16 hh = (_Float16)fe[e];
            hi8[e] = hh;
            lo8[e] = (_Float16)(fe[e] - (float)hh);
        }
        *(f16x8*)&cah[buf][st_h][st_r][st_c * 8] = hi8;
        *(f16x8*)&cal[buf][st_h][st_r][st_c * 8] = lo8;
    };

    STAGE(0, 0);
    __syncthreads();

    for (int t = 0; t < 8; ++t) {          // 8 tiles of 64 candidates
        if (t < 7) STAGE((t + 1) & 1, t + 1);
        int buf = t & 1;
        #pragma unroll
        for (int sub = 0; sub < 4; ++sub) {       // 4 subtiles of 16 cands
            f16x8 Ahi = *(const f16x8*)&cah[buf][half][sub * 16 + n][kc * 8];
            f16x8 Alo = *(const f16x8*)&cal[buf][half][sub * 16 + n][kc * 8];
            v4f acc = { 0.f, 0.f, 0.f, 0.f };
            acc = __builtin_amdgcn_mfma_f32_16x16x32_f16(Ahi, Bhi, acc, 0, 0, 0);
            acc = __builtin_amdgcn_mfma_f32_16x16x32_f16(Ahi, Blo, acc, 0, 0, 0);
            acc = __builtin_amdgcn_mfma_f32_16x16x32_f16(Alo, Bhi, acc, 0, 0, 0);
            // hsq20 of this lane's 4 candidates
            const float4 hv = *(const float4*)(sqb + half * 512 + t * 64
                                               + sub * 16 + kc * 4);
            int t7b = (t << 4) | (sub << 2);
            float k0f = fmaf(acc[0], -1048576.0f, cinit20 + hv.x);
            float k1f = fmaf(acc[1], -1048576.0f, cinit20 + hv.y);
            float k2f = fmaf(acc[2], -1048576.0f, cinit20 + hv.z);
            float k3f = fmaf(acc[3], -1048576.0f, cinit20 + hv.w);
            unsigned p0 = (umn((unsigned)k0f, 0x1FFFFFFu) << 7) | (unsigned)(t7b + 0);
            unsigned p1 = (umn((unsigned)k1f, 0x1FFFFFFu) << 7) | (unsigned)(t7b + 1);
            unsigned p2 = (umn((unsigned)k2f, 0x1FFFFFFu) << 7) | (unsigned)(t7b + 2);
            unsigned p3 = (umn((unsigned)k3f, 0x1FFFFFFu) << 7) | (unsigned)(t7b + 3);
            p0 = (t7b + 0 == self_t7) ? 0xFFFFFFFFu : p0;
            p1 = (t7b + 1 == self_t7) ? 0xFFFFFFFFu : p1;
            p2 = (t7b + 2 == self_t7) ? 0xFFFFFFFFu : p2;
            p3 = (t7b + 3 == self_t7) ? 0xFFFFFFFFu : p3;
            INSERT_PAIR(p0, p1);
            INSERT_PAIR(p2, p3);
        }
        __syncthreads();
    }

    // partial id: half*4 + lane-row-quad; target-in-block = gtg*16 + n
    {
        int p  = half * 4 + kc;
        int tr = gtg * 16 + n;
        s_key[p][tr][0] = bd0; s_key[p][tr][1] = bd1;
        s_key[p][tr][2] = bd2; s_key[p][tr][3] = bd3;
        s_key[p][tr][4] = bd4; s_key[p][tr][5] = bd5;
        s_key[p][tr][6] = bd6; s_key[p][tr][7] = bd7;
        s_key[p][tr][8] = bd8; s_key[p][tr][9] = bd9;
    }
    __syncthreads();

    if (wid == 0) {
        // 8-way merge of sorted 10-lists per target (lane = target 0..63)
        unsigned k0 = s_key[0][lane][0], k1 = s_key[1][lane][0];
        unsigned k2 = s_key[2][lane][0], k3 = s_key[3][lane][0];
        unsigned k4 = s_key[4][lane][0], k5 = s_key[5][lane][0];
        unsigned k6 = s_key[6][lane][0], k7 = s_key[7][lane][0];
        int q0=0,q1=0,q2=0,q3=0,q4=0,q5=0,q6=0,q7=0;
        float wsum = 0.f;
        #pragma unroll
        for (int j = 0; j < KNN; ++j) {
            unsigned mn = k0; int c = 0;
            if (k1 < mn) { mn = k1; c = 1; }
            if (k2 < mn) { mn = k2; c = 2; }
            if (k3 < mn) { mn = k3; c = 3; }
            if (k4 < mn) { mn = k4; c = 4; }
            if (k5 < mn) { mn = k5; c = 5; }
            if (k6 < mn) { mn = k6; c = 6; }
            if (k7 < mn) { mn = k7; c = 7; }
            int t7 = (int)(mn & 127u);
            int abs_ = ((c >> 2) << 9) + ((t7 >> 4) << 6) + (((t7 >> 2) & 3) << 4)
                       + ((c & 3) << 2) + (t7 & 3);
            float kf = (float)(mn >> 7) * 9.5367431640625e-07f;
            float wk = expf(1.0f - kf);               // exp(-0.5*d2)
            wsum += wk;
            e_id[lane][j] = (short)abs_;
            e_wk[lane][j] = wk;
            if      (c == 0) { ++q0; k0 = (q0 < KNN) ? s_key[0][lane][q0] : 0xFFFFFFFFu; }
            else if (c == 1) { ++q1; k1 = (q1 < KNN) ? s_key[1][lane][q1] : 0xFFFFFFFFu; }
            else if (c == 2) { ++q2; k2 = (q2 < KNN) ? s_key[2][lane][q2] : 0xFFFFFFFFu; }
            else if (c == 3) { ++q3; k3 = (q3 < KNN) ? s_key[3][lane][q3] : 0xFFFFFFFFu; }
            else if (c == 4) { ++q4; k4 = (q4 < KNN) ? s_key[4][lane][q4] : 0xFFFFFFFFu; }
            else if (c == 5) { ++q5; k5 = (q5 < KNN) ? s_key[5][lane][q5] : 0xFFFFFFFFu; }
            else if (c == 6) { ++q6; k6 = (q6 < KNN) ? s_key[6][lane][q6] : 0xFFFFFFFFu; }
            else             { ++q7; k7 = (q7 < KNN) ? s_key[7][lane][q7] : 0xFFFFFFFFu; }
        }
        e_inv[lane] = 1.0f / (wsum + 1e-8f);
    }
    __syncthreads();

    // gather + smooth + tanh, parallel over (row, 4-dim group); a_pool
    // aliases s_key (dead after merge). Stride 36 -> 16B-aligned rows.
    float* a_pool = (float*)&s_key[0][0][0];
    {
        int r  = tid >> 3;             // 0..63
        int g2 = (tid & 7) << 2;       // dim base 0,4,...,28
        float ax = 0.f, ay = 0.f, az = 0.f, aw = 0.f;
        #pragma unroll
        for (int k = 0; k < KNN; ++k) {
            int idx  = e_id[r][k];
            float wk = e_wk[r][k];
            const float4 nv = *(const float4*)(hb + (size_t)idx * HH + g2);
            ax = fmaf(wk, nv.x, ax);
            ay = fmaf(wk, nv.y, ay);
            az = fmaf(wk, nv.z, az);
            aw = fmaf(wk, nv.w, aw);
        }
        float inv = e_inv[r];
        const float4 hv = *(const float4*)(hb + (size_t)(rb + r) * HH + g2);
        float4 av;
        av.x = tanhf(fmaf(-ax, inv, hv.x));
        av.y = tanhf(fmaf(-ay, inv, hv.y));
        av.z = tanhf(fmaf(-az, inv, hv.z));
        av.w = tanhf(fmaf(-aw, inv, hv.w));
        *(float4*)&a_pool[r * 36 + g2] = av;
    }
    __syncthreads();

    // out = a @ W2 + b2 ; thread -> (row r, 4 consecutive output dims)
    int r   = tid >> 3;
    int c0_ = (tid & 7) << 2;
    float o[4];
    #pragma unroll
    for (int u = 0; u < 4; ++u) o[u] = b2s[c0_ + u];
    #pragma unroll
    for (int j = 0; j < HH; ++j) {
        float av = a_pool[r * 36 + j];
        #pragma unroll
        for (int u = 0; u < 4; ++u) o[u] = fmaf(av, w2s[j][c0_ + u], o[u]);
    }
    float* op = out + ((size_t)bb * TT + rb + r) * HH + c0_;
    float4 o1 = { o[0], o[1], o[2], o[3] };
    *((float4*)op) = o1;
}

extern "C" void kernel_launch(void* const* d_in, const int* in_sizes, int n_in,
                              void* d_out, int out_size, void* d_ws, size_t ws_size,
                              hipStream_t stream) {
    const float* x  = (const float*)d_in[0];
    const float* W1 = (const float*)d_in[1];
    const float* b1 = (const float*)d_in[2];
    const float* W2 = (const float*)d_in[3];
    const float* b2 = (const float*)d_in[4];
    float* outp = (float*)d_out;

    float* h   = (float*)d_ws;
    float* hsq = h + (size_t)BB * TT * HH;

    h_kernel<<<(BB * TT) / 256, 256, 0, stream>>>(x, W1, b1, h, hsq);
    lap_kernel<<<BB * (TT / 64), 512, 0, stream>>>(h, hsq, W2, b2, outp);
}